// Round 9
// baseline (304.073 us; speedup 1.0000x reference)
//
#include <hip/hip_runtime.h>
#include <hip/hip_bf16.h>

#define D128 128

typedef __attribute__((ext_vector_type(8))) short bf16x8;
typedef __attribute__((ext_vector_type(4))) float f32x4;

__device__ __forceinline__ float b2f(unsigned short u) {
    union { unsigned int i; float f; } z;
    z.i = ((unsigned int)u) << 16;
    return z.f;
}

__device__ __forceinline__ unsigned short f2b(float f) {
    union { float f; unsigned int i; } z;
    z.f = f;
    unsigned int r = z.i + 0x7FFFu + ((z.i >> 16) & 1u);  // round-to-nearest-even
    return (unsigned short)(r >> 16);
}

__device__ __forceinline__ f32x4 mfma16(bf16x8 a, bf16x8 b, f32x4 c) {
    return __builtin_amdgcn_mfma_f32_16x16x32_bf16(a, b, c, 0, 0, 0);
}

#define CHUNK2 4096    // edges per scatter block
#define BINW   128     // dsts per bin
#define BINCAP 4096    // slots per bin region (mean fill ~2046, >40 sigma)
#define MAXBINS 1024
#define NGB 768        // persistent GEMM blocks
#define NFB 768        // persistent final-GEMM blocks

// ---------------------------------------------------------------------------
// k_prep (3-way block partition):
//   blocks [0,68)     : compose rows 0..135 of Wcat directly:
//                       rows 0..127  = (Wg @ W1) packed fragment-major
//                       rows 128..135 = att-folded virtual rows (vg = att@Wg,
//                       then vg@W1); lbias written per-row. Rows 136..143 of
//                       Wcat stay zero (memset upfront).
//   blocks [68,76)    : W2l fragment-major relayout of W2
//   blocks [76,76+B)  : padded-bin scatter: two-pass LDS count -> global
//                       reserve (one atomicAdd per bin per block) -> write
//                       packed (dlocal<<20|src) into binned[bin*BINCAP+pos]
// ---------------------------------------------------------------------------
__global__ __launch_bounds__(256) void k_prep(
    const float* __restrict__ W1, const float* __restrict__ Wg,
    const float* __restrict__ b1,
    const float* __restrict__ att_s, const float* __restrict__ att_d,
    const float* __restrict__ W2,
    const int* __restrict__ ei,
    unsigned short* __restrict__ Wcat, unsigned short* __restrict__ W2l,
    float* __restrict__ lbias,
    unsigned int* __restrict__ binned, int* __restrict__ binFill,
    int E, int B, int nbins)
{
    const int t = threadIdx.x;
    const int b = blockIdx.x;
    if (b < 68) {
        __shared__ float wgr[256];
        __shared__ float rowout[2][128];
        if (b < 64) {
            const int i0 = b * 2;
            wgr[t] = Wg[i0 * 128 + t];               // rows i0, i0+1
        } else {
            // virtual att rows: vg[q][k] = sum_c av[h*32+c] * Wg[h*32+c][k]
            const int q = (b - 64) * 2 + (t >> 7);   // 0..7
            const int h = q & 3;
            const float* av = q < 4 ? att_s : att_d;
            const int k = t & 127;
            float v = 0.f;
            #pragma unroll 8
            for (int c = 0; c < 32; ++c)
                v += av[h * 32 + c] * Wg[(h * 32 + c) * 128 + k];
            wgr[t] = v;
        }
        __syncthreads();
        const int half = t >> 7;
        const int j = t & 127;
        const float* wr = &wgr[half * 128];
        float acc = 0.f;
        #pragma unroll 4
        for (int k = 0; k < 128; ++k)
            acc += wr[k] * W1[k * 128 + j];
        rowout[half][j] = acc;
        if (j == 0) {
            float ab = 0.f;
            for (int k = 0; k < 128; ++k) ab += wr[k] * b1[k];
            const int rho = (b < 64) ? b * 2 + half : 128 + (b - 64) * 2 + half;
            lbias[rho] = ab;
        }
        __syncthreads();
        if (t < 32) {
            const int half2 = t >> 4;
            const int rho = (b < 64) ? b * 2 + half2 : 128 + (b - 64) * 2 + half2;
            const int idx16 = t & 15;
            const int ks = idx16 >> 2, ldiv = idx16 & 3;
            const int colb = ks * 32 + ldiv * 8;
            const int ct = rho >> 4, lmod = rho & 15;
            const int frag = (ct * 4 + ks) * 64 + ldiv * 16 + lmod;
            union { uint4 q4; unsigned short s[8]; } o;
            #pragma unroll
            for (int e = 0; e < 8; ++e) o.s[e] = f2b(rowout[half2][colb + e]);
            *(uint4*)(Wcat + frag * 8) = o.q4;
        }
    } else if (b < 76) {
        const int q = (b - 68) * 256 + t;     // 0..2047
        const int ct = q >> 8, rem = q & 255;
        const int ks = rem >> 6, lane = rem & 63;
        const int ldiv = lane >> 4, lmod = lane & 15;
        const int kb = ks * 32 + ldiv * 8;
        const int rho = ct * 16 + lmod;
        const float4 a = *(const float4*)(W2 + rho * 128 + kb);
        const float4 bq = *(const float4*)(W2 + rho * 128 + kb + 4);
        union { uint4 qq; unsigned short s[8]; } o;
        o.s[0] = f2b(a.x); o.s[1] = f2b(a.y); o.s[2] = f2b(a.z); o.s[3] = f2b(a.w);
        o.s[4] = f2b(bq.x); o.s[5] = f2b(bq.y); o.s[6] = f2b(bq.z); o.s[7] = f2b(bq.w);
        *(uint4*)(W2l + q * 8) = o.qq;
    } else {
        __shared__ int hist[MAXBINS];
        const int chunk = b - 76;
        for (int i = t; i < nbins; i += 256) hist[i] = 0;
        __syncthreads();
        const int base = chunk * CHUNK2;
        const int end = min(base + CHUNK2, E);
        for (int e = base + t; e < end; e += 256)
            atomicAdd(&hist[ei[E + e] >> 7], 1);
        __syncthreads();
        for (int i = t; i < nbins; i += 256) {
            const int c = hist[i];
            hist[i] = c > 0 ? atomicAdd(&binFill[i], c) : 0;   // reserve
        }
        __syncthreads();
        for (int e = base + t; e < end; e += 256) {
            const int s = ei[e], d = ei[E + e];
            const int bin = d >> 7;
            const int pos = atomicAdd(&hist[bin], 1);          // LDS cursor
            if (pos < BINCAP)
                binned[(size_t)bin * BINCAP + pos] =
                    ((unsigned int)(d & 127) << 20) | (unsigned int)s;
        }
    }
}

// ---------------------------------------------------------------------------
// k_mid (2-way block partition):
//   blocks [0, nbins)       : per-bin CSR in LDS -> bucket (padded regions)
//                             + rowstart/rowend
//   blocks [nbins, +NGB)    : persistent GEMM: Wcat->LDS once, grid-stride
//                             over 64-row tiles: h = leaky(x)@Wcat^T ->
//                             hfeat + asrc/adst
// ---------------------------------------------------------------------------
__global__ __launch_bounds__(256) void k_mid(
    const float* __restrict__ x,
    const unsigned short* __restrict__ Wcat,
    const float* __restrict__ lbias,
    unsigned short* __restrict__ hfeat,
    float* __restrict__ asrc, float* __restrict__ adst,
    const unsigned int* __restrict__ binned, const int* __restrict__ binFill,
    int* __restrict__ bucket,
    int* __restrict__ rowstart, int* __restrict__ rowend,
    int N, int nbins, int ntiles)
{
    __shared__ __align__(16) unsigned char smem[36864];
    const int t = threadIdx.x;
    if (blockIdx.x < nbins) {
        unsigned int* eb = (unsigned int*)smem;            // 4096 uints, 16 KB
        int* ldeg  = (int*)(smem + 16384);                 // 128
        int* lscan = ldeg + 128;                           // 128
        int* lcur  = lscan + 128;                          // 128
        const int bin = blockIdx.x;
        int n = binFill[bin];
        if (n > BINCAP) n = BINCAP;
        const int bb = bin * BINCAP;
        for (int i = t; i < n; i += 256) eb[i] = binned[(size_t)bb + i];
        if (t < 128) ldeg[t] = 0;
        __syncthreads();
        for (int i = t; i < n; i += 256)
            atomicAdd(&ldeg[eb[i] >> 20], 1);
        __syncthreads();
        int v = 0;
        if (t < 128) { v = ldeg[t]; lscan[t] = v; }
        __syncthreads();
        #pragma unroll
        for (int off = 1; off < 128; off <<= 1) {
            int tv = (t < 128 && t >= off) ? lscan[t - off] : 0;
            __syncthreads();
            if (t < 128) lscan[t] += tv;
            __syncthreads();
        }
        if (t < 128) {
            const int excl = lscan[t] - v;
            lcur[t] = excl;
            const int d = (bin << 7) + t;
            if (d < N) {
                rowstart[d] = bb + excl;
                rowend[d]   = bb + excl + v;
            }
        }
        __syncthreads();
        for (int i = t; i < n; i += 256) {
            const unsigned int p = eb[i];
            const int lp = atomicAdd(&lcur[p >> 20], 1);   // LDS atomic
            bucket[(size_t)bb + lp] = (int)(p & 0xFFFFFu);
        }
    } else {
        unsigned short* sW = (unsigned short*)smem;
        const int wave = t >> 6, lane = t & 63, lmod = lane & 15, ldiv = lane >> 4;

        #pragma unroll
        for (int r = 0; r < 9; ++r)
            *(uint4*)&sW[r * 2048 + t * 8] = *(const uint4*)(Wcat + r * 2048 + t * 8);
        __syncthreads();

        for (int tile = blockIdx.x - nbins; tile < ntiles; tile += NGB) {
            const int rowBase = tile * 64;
            int row = rowBase + wave * 16 + lmod;
            row = min(row, N - 1);
            bf16x8 afr[4];
            #pragma unroll
            for (int ks = 0; ks < 4; ++ks) {
                const float* px = x + (size_t)row * D128 + ks * 32 + ldiv * 8;
                float4 f0 = *(const float4*)px;
                float4 f1 = *(const float4*)(px + 4);
                float tmp[8] = { f0.x, f0.y, f0.z, f0.w, f1.x, f1.y, f1.z, f1.w };
                union { bf16x8 v; unsigned short s[8]; } o;
                #pragma unroll
                for (int jj = 0; jj < 8; ++jj) {
                    float f = tmp[jj];
                    f = f >= 0.f ? f : 0.01f * f;
                    o.s[jj] = f2b(f);
                }
                afr[ks] = o.v;
            }

            f32x4 acc[9] = {};
            #pragma unroll
            for (int ct = 0; ct < 9; ++ct) {
                #pragma unroll
                for (int ks = 0; ks < 4; ++ks) {
                    bf16x8 bfr = *(const bf16x8*)&sW[(ct * 256 + ks * 64 + lane) * 8];
                    acc[ct] = mfma16(afr[ks], bfr, acc[ct]);
                }
            }

            const int orow = rowBase + wave * 16 + ldiv * 4;
            #pragma unroll
            for (int ct = 0; ct < 8; ++ct) {
                const int col = ct * 16 + lmod;
                const float bias = lbias[col];
                #pragma unroll
                for (int r = 0; r < 4; ++r)
                    if (orow + r < N)
                        hfeat[(size_t)(orow + r) * D128 + col] = f2b(acc[ct][r] + bias);
            }
            if (lmod < 8) {
                const float lb = lbias[128 + lmod];
                float* dst = lmod < 4 ? asrc : adst;
                const int hh = lmod & 3;
                #pragma unroll
                for (int r = 0; r < 4; ++r)
                    if (orow + r < N)
                        dst[(size_t)(orow + r) * 4 + hh] = acc[8][r] + lb;
            }
        }
    }
}

// ---------------------------------------------------------------------------
// GAT aggregation, 16 lanes per dst, depth-2 (unchanged, measured floor).
// ---------------------------------------------------------------------------
__global__ __launch_bounds__(256) void k_gat(
    const int* __restrict__ bucket,
    const int* __restrict__ rowstart, const int* __restrict__ rowend,
    const float* __restrict__ asrc, const float* __restrict__ adst,
    const unsigned short* __restrict__ hfeat,
    const float* __restrict__ bias_g,
    unsigned short* __restrict__ outbf, int N)
{
    const int wave = threadIdx.x >> 6;
    const int lane = threadIdx.x & 63;
    const int g    = lane >> 4;          // dst-group within wave (0..3)
    const int gl   = lane & 15;          // lane within group
    const int h    = gl >> 2;            // head 0..3
    const int d    = blockIdx.x * 16 + wave * 4 + g;

    int start = 0, end = 0;
    float a_d = 0.f;
    if (d < N) {
        start = rowstart[d];
        end   = rowend[d];
        a_d   = adst[(size_t)d * 4 + h];
    }
    const unsigned int chb = (unsigned int)(gl << 3);   // channel offset (elems)
    const unsigned short* hbase = hfeat + chb;

    float acc[8] = {0.f, 0.f, 0.f, 0.f, 0.f, 0.f, 0.f, 0.f};
    float denom = 0.f;

    int j = start;
    for (; j + 2 <= end; j += 2) {
        const int s0 = bucket[j];
        const int s1 = bucket[j + 1];
        const float as0 = asrc[((size_t)s0 << 2) + h];
        const float as1 = asrc[((size_t)s1 << 2) + h];
        const uint4 hp0 = *(const uint4*)(hbase + ((unsigned int)s0 << 7));
        const uint4 hp1 = *(const uint4*)(hbase + ((unsigned int)s1 << 7));
        float a0 = as0 + a_d; a0 = a0 >= 0.f ? a0 : 0.2f * a0;
        float a1 = as1 + a_d; a1 = a1 >= 0.f ? a1 : 0.2f * a1;
        const float w0 = __expf(a0), w1 = __expf(a1);
        denom += w0 + w1;
        acc[0] += w0 * b2f((unsigned short)(hp0.x & 0xFFFFu)) + w1 * b2f((unsigned short)(hp1.x & 0xFFFFu));
        acc[1] += w0 * b2f((unsigned short)(hp0.x >> 16))     + w1 * b2f((unsigned short)(hp1.x >> 16));
        acc[2] += w0 * b2f((unsigned short)(hp0.y & 0xFFFFu)) + w1 * b2f((unsigned short)(hp1.y & 0xFFFFu));
        acc[3] += w0 * b2f((unsigned short)(hp0.y >> 16))     + w1 * b2f((unsigned short)(hp1.y >> 16));
        acc[4] += w0 * b2f((unsigned short)(hp0.z & 0xFFFFu)) + w1 * b2f((unsigned short)(hp1.z & 0xFFFFu));
        acc[5] += w0 * b2f((unsigned short)(hp0.z >> 16))     + w1 * b2f((unsigned short)(hp1.z >> 16));
        acc[6] += w0 * b2f((unsigned short)(hp0.w & 0xFFFFu)) + w1 * b2f((unsigned short)(hp1.w & 0xFFFFu));
        acc[7] += w0 * b2f((unsigned short)(hp0.w >> 16))     + w1 * b2f((unsigned short)(hp1.w >> 16));
    }
    if (j < end) {
        const int s0 = bucket[j];
        const float as0 = asrc[((size_t)s0 << 2) + h];
        const uint4 hp0 = *(const uint4*)(hbase + ((unsigned int)s0 << 7));
        float a0 = as0 + a_d; a0 = a0 >= 0.f ? a0 : 0.2f * a0;
        const float w0 = __expf(a0);
        denom += w0;
        acc[0] += w0 * b2f((unsigned short)(hp0.x & 0xFFFFu));
        acc[1] += w0 * b2f((unsigned short)(hp0.x >> 16));
        acc[2] += w0 * b2f((unsigned short)(hp0.y & 0xFFFFu));
        acc[3] += w0 * b2f((unsigned short)(hp0.y >> 16));
        acc[4] += w0 * b2f((unsigned short)(hp0.z & 0xFFFFu));
        acc[5] += w0 * b2f((unsigned short)(hp0.z >> 16));
        acc[6] += w0 * b2f((unsigned short)(hp0.w & 0xFFFFu));
        acc[7] += w0 * b2f((unsigned short)(hp0.w >> 16));
    }

    if (d < N) {
        const float inv = 1.f / (denom + 1e-16f);
        const float4 bg0 = *(const float4*)(bias_g + chb);
        const float4 bg1 = *(const float4*)(bias_g + chb + 4);
        const float bg[8] = { bg0.x, bg0.y, bg0.z, bg0.w, bg1.x, bg1.y, bg1.z, bg1.w };
        unsigned short s[8];
        #pragma unroll
        for (int k2 = 0; k2 < 8; ++k2) {
            float v = acc[k2] * inv + bg[k2];
            v = v >= 0.f ? v : 0.01f * v;
            s[k2] = f2b(v);
        }
        uint4 o;
        o.x = ((unsigned int)s[1] << 16) | s[0];
        o.y = ((unsigned int)s[3] << 16) | s[2];
        o.z = ((unsigned int)s[5] << 16) | s[4];
        o.w = ((unsigned int)s[7] << 16) | s[6];
        *(uint4*)(outbf + (((unsigned int)d << 7) + chb)) = o;
    }
}

// ---------------------------------------------------------------------------
// PERSISTENT final GEMM (unchanged from round 8).
// ---------------------------------------------------------------------------
__global__ __launch_bounds__(256) void k_final(
    const unsigned short* __restrict__ gatbf,
    const unsigned short* __restrict__ W2l,
    const float* __restrict__ b2,
    float* __restrict__ out, int N, int ntiles)
{
    __shared__ __align__(16) unsigned short sW[16384];   // 32768 B
    const int t = threadIdx.x;
    const int wave = t >> 6, lane = t & 63, lmod = lane & 15, ldiv = lane >> 4;

    #pragma unroll
    for (int r = 0; r < 8; ++r)
        *(uint4*)&sW[r * 2048 + t * 8] = *(const uint4*)(W2l + r * 2048 + t * 8);
    __syncthreads();

    for (int tile = blockIdx.x; tile < ntiles; tile += NFB) {
        const int rowBase = tile * 64;
        int row = rowBase + wave * 16 + lmod;
        row = min(row, N - 1);
        bf16x8 afr[4];
        #pragma unroll
        for (int ks = 0; ks < 4; ++ks)
            afr[ks] = *(const bf16x8*)(gatbf + (size_t)row * D128 + ks * 32 + ldiv * 8);

        f32x4 acc[8] = {};
        #pragma unroll
        for (int ct = 0; ct < 8; ++ct) {
            #pragma unroll
            for (int ks = 0; ks < 4; ++ks) {
                bf16x8 bfr = *(const bf16x8*)&sW[(ct * 256 + ks * 64 + lane) * 8];
                acc[ct] = mfma16(afr[ks], bfr, acc[ct]);
            }
        }

        const int orow = rowBase + wave * 16 + ldiv * 4;
        #pragma unroll
        for (int ct = 0; ct < 8; ++ct) {
            const int col = ct * 16 + lmod;
            const float bb = b2[col];
            #pragma unroll
            for (int r = 0; r < 4; ++r)
                if (orow + r < N)
                    out[(size_t)(orow + r) * D128 + col] = acc[ct][r] + bb;
        }
    }
}

// ---------------------------------------------------------------------------
extern "C" void kernel_launch(void* const* d_in, const int* in_sizes, int n_in,
                              void* d_out, int out_size, void* d_ws, size_t ws_size,
                              hipStream_t stream)
{
    const float* x    = (const float*)d_in[0];
    const int*   ei   = (const int*)d_in[1];
    // d_in[2] edge_type: unused by forward
    const float* W1   = (const float*)d_in[3];
    const float* b1   = (const float*)d_in[4];
    const float* Wg   = (const float*)d_in[5];
    const float* atts = (const float*)d_in[6];
    const float* attd = (const float*)d_in[7];
    const float* bg   = (const float*)d_in[8];
    const float* W2   = (const float*)d_in[9];
    const float* b2   = (const float*)d_in[10];
    float* out = (float*)d_out;

    const int N = in_sizes[0] / D128;
    const int E = in_sizes[1] / 2;

    const int B      = (E + CHUNK2 - 1) / CHUNK2;     // scatter chunks
    const int nbins  = (N + BINW - 1) / BINW;         // 128-dst bins
    const int ntiles = (N + 63) / 64;

    // workspace layout (16B aligned pieces)
    char* ws = (char*)d_ws;
    size_t off = 0;
    unsigned short* Wcat = (unsigned short*)(ws + off); off += 36864;
    unsigned short* W2l  = (unsigned short*)(ws + off); off += 32768;
    float* lbias = (float*)(ws + off); off += 1024;
    int* binFill = (int*)(ws + off); off += (size_t)((nbins * 4 + 15) & ~15);
    unsigned short* hfeat = (unsigned short*)(ws + off); off += (size_t)N * D128 * 2;
    float* asrc = (float*)(ws + off); off += (size_t)N * 4 * 4;
    float* adst = (float*)(ws + off); off += (size_t)N * 4 * 4;
    unsigned int* binned = (unsigned int*)(ws + off); off += (size_t)nbins * BINCAP * 4;
    int* bucket  = (int*)(ws + off); off += (size_t)nbins * BINCAP * 4;
    int* rowstart = (int*)(ws + off); off += (size_t)N * 4;
    int* rowend   = (int*)(ws + off); off += (size_t)N * 4;
    unsigned short* outbf = (unsigned short*)(ws + off); off += (size_t)N * D128 * 2;

    // zero-init: Wcat rows 136..143 stay zero; binFill counters start at 0
    hipMemsetAsync(Wcat, 0, 36864, stream);
    hipMemsetAsync(binFill, 0, (size_t)nbins * 4, stream);

    // 1) compose+pack weights, W2 relayout, padded-bin edge scatter
    k_prep<<<76 + B, 256, 0, stream>>>(W1, Wg, b1, atts, attd, W2, ei,
                                       Wcat, W2l, lbias, binned, binFill,
                                       E, B, nbins);
    // 2) per-bin CSR + persistent h/logits GEMM (co-scheduled)
    k_mid<<<nbins + NGB, 256, 0, stream>>>(x, Wcat, lbias, hfeat, asrc, adst,
                                           binned, binFill, bucket,
                                           rowstart, rowend, N, nbins, ntiles);
    // 3) gather-style GAT aggregation (fused softmax + bias_g + leaky)
    k_gat<<<(N + 15) / 16, 256, 0, stream>>>(bucket, rowstart, rowend,
                                             asrc, adst, hfeat, bg, outbf, N);
    // 4) persistent final GEMM
    k_final<<<NFB, 256, 0, stream>>>(outbf, W2l, b2, out, N, ntiles);
}